// Round 8
// baseline (148.870 us; speedup 1.0000x reference)
//
#include <hip/hip_runtime.h>
#include <hip/hip_bf16.h>

#define CCH 256

typedef float f4 __attribute__((ext_vector_type(4)));

// ---------------- Kernel 1a: pool rgb + dep (nontemporal) ----------------
__global__ __launch_bounds__(256, 2) void poolA_kernel(
    const float* __restrict__ rgb, const float* __restrict__ dep,
    float* __restrict__ nodes /* [32][4][256] */)
{
    const int rw   = blockIdx.x * 4 + (threadIdx.x >> 6);  // 0..16383
    const int lane = threadIdx.x & 63;
    const int tensor = rw >> 13;              // 0 = rgb, 1 = dep
    const int row    = rw & 8191;             // b*256 + c
    const f4* src = (const f4*)((tensor ? dep : rgb) + (size_t)row * 4096);

    f4 v[16];
#pragma unroll
    for (int j = 0; j < 16; ++j) v[j] = __builtin_nontemporal_load(src + lane + 64 * j);
    f4 a0 = v[0] + v[1], a1 = v[2] + v[3], a2 = v[4] + v[5], a3 = v[6] + v[7];
    f4 a4 = v[8] + v[9], a5 = v[10] + v[11], a6 = v[12] + v[13], a7 = v[14] + v[15];
    f4 acc = ((a0 + a1) + (a2 + a3)) + ((a4 + a5) + (a6 + a7));

    float s = acc.x + acc.y + acc.z + acc.w;
#pragma unroll
    for (int off = 32; off; off >>= 1) s += __shfl_down(s, off, 64);
    if (lane == 0) {
        const int b = row >> 8, c = row & 255;
        nodes[(size_t)b * 1024 + (2 + tensor) * CCH + c] = s * (1.f / 4096.f);
    }
}

// ---------------- Kernel 1b: pool x_ful (temporal — keep in L3 for apply) ----------------
__global__ __launch_bounds__(256, 2) void poolB_kernel(
    const float* __restrict__ xf, float* __restrict__ nodes)
{
    const int row  = blockIdx.x * 4 + (threadIdx.x >> 6);  // 0..8191
    const int lane = threadIdx.x & 63;
    const f4* src = (const f4*)(xf + (size_t)row * 4096);

    f4 v[16];
#pragma unroll
    for (int j = 0; j < 16; ++j) v[j] = src[lane + 64 * j];
    f4 a0 = v[0] + v[1], a1 = v[2] + v[3], a2 = v[4] + v[5], a3 = v[6] + v[7];
    f4 a4 = v[8] + v[9], a5 = v[10] + v[11], a6 = v[12] + v[13], a7 = v[14] + v[15];
    f4 acc = ((a0 + a1) + (a2 + a3)) + ((a4 + a5) + (a6 + a7));

    float s = acc.x + acc.y + acc.z + acc.w;
#pragma unroll
    for (int off = 32; off; off >>= 1) s += __shfl_down(s, off, 64);
    if (lane == 0) {
        const int b = row >> 8, c = row & 255;
        nodes[(size_t)b * 1024 + 1 * CCH + c] = s * (1.f / 4096.f);
    }
}

// ---------------- Kernel 2: full 2-layer GAT in ONE kernel ----------------
// grid: 32 blocks (batch), 1024 threads: h = t>>8, c = t&255.
// Thread (h,c) owns xp column h*256+c for all 4 nodes (acc[4] in registers),
// and owns node d=h channel c in the LN phase. W staged 16-deep in registers;
// X read from LDS as float4 (4x fewer ds_reads across 16 waves).
__global__ __launch_bounds__(1024) void gat_kernel(
    const float* __restrict__ nodes, const float* __restrict__ tok,
    float* __restrict__ scale,
    const float* __restrict__ W0, const float* __restrict__ as0,
    const float* __restrict__ ad0, const float* __restrict__ b0,
    const float* __restrict__ g0, const float* __restrict__ be0,
    const float* __restrict__ W1, const float* __restrict__ as1,
    const float* __restrict__ ad1, const float* __restrict__ b1,
    const float* __restrict__ g1, const float* __restrict__ be1)
{
    const int t = threadIdx.x;           // 0..1023
    const int b = blockIdx.x;
    const int h = t >> 8, c = t & 255;
    const int lane = t & 63, wv = t >> 6;    // wv 0..15

    __shared__ float X[4][CCH];          // node features (16B-aligned rows for f4)
    __shared__ float redl[16][8];        // per-wave logit partials
    __shared__ float esed[4][8];         // [h][ es(n)=0..3 | ed(n)=4..7 ]
    __shared__ float alpha_s[4][4][4];   // [h][dst][slot]
    __shared__ float msum[4][4][CCH];    // [h][dst][c] per-head messages (16 KB)
    __shared__ float red2[16][2];        // per-wave LN partials
    __shared__ float mu_s[4], rstd_s[4];

    if (t < 256) {
        X[0][c] = tok[c];
        X[1][c] = nodes[(size_t)b * 1024 + 256 + c];
        X[2][c] = nodes[(size_t)b * 1024 + 512 + c];
        X[3][c] = nodes[(size_t)b * 1024 + 768 + c];
    }
    __syncthreads();

    for (int layer = 0; layer < 2; ++layer) {
        const float* W  = layer ? W1  : W0;
        const float* As = layer ? as1 : as0;
        const float* Ad = layer ? ad1 : ad0;
        const float* Bi = layer ? b1  : b0;
        const float* Ga = layer ? g1  : g0;
        const float* Be = layer ? be1 : be0;

        // ---- GEMM: acc[n] = sum_k X[n][k] * W[k][h*256+c], 16-deep W staging
        float acc[4] = {0.f, 0.f, 0.f, 0.f};
        const float* Wp = W + h * 256 + c;
        for (int k0 = 0; k0 < 256; k0 += 16) {
            float wr[16];
#pragma unroll
            for (int u = 0; u < 16; ++u) wr[u] = Wp[(size_t)(k0 + u) * 1024];
#pragma unroll
            for (int q = 0; q < 4; ++q) {
                f4 x0 = *(const f4*)&X[0][k0 + 4 * q];
                f4 x1 = *(const f4*)&X[1][k0 + 4 * q];
                f4 x2 = *(const f4*)&X[2][k0 + 4 * q];
                f4 x3 = *(const f4*)&X[3][k0 + 4 * q];
#pragma unroll
                for (int e = 0; e < 4; ++e) {
                    float w = wr[4 * q + e];
                    acc[0] += x0[e] * w;
                    acc[1] += x1[e] * w;
                    acc[2] += x2[e] * w;
                    acc[3] += x3[e] * w;
                }
            }
        }

        // ---- logits: 8 reductions over c within each head's 4 waves
        const float av = As[h * 256 + c], dv = Ad[h * 256 + c];
        float rv[8];
#pragma unroll
        for (int n = 0; n < 4; ++n) { rv[n] = acc[n] * av; rv[4 + n] = acc[n] * dv; }
#pragma unroll
        for (int i = 0; i < 8; ++i)
#pragma unroll
            for (int off = 32; off; off >>= 1)
                rv[i] += __shfl_down(rv[i], off, 64);
        if (lane == 0) {
#pragma unroll
            for (int i = 0; i < 8; ++i) redl[wv][i] = rv[i];
        }
        __syncthreads();
        if (t < 32) {
            const int hh = t >> 3, i = t & 7;
            esed[hh][i] = redl[4*hh][i] + redl[4*hh+1][i] + redl[4*hh+2][i] + redl[4*hh+3][i];
        }
        __syncthreads();

        // ---- segment softmax per (head, dst): 16 threads
        if (t < 16) {
            const int hh = t & 3, d = t >> 2;
            const int cnt[4]     = {4, 3, 3, 3};
            const int srcs[4][4] = {{1,2,3,0},{2,3,1,0},{1,3,2,0},{1,2,3,0}};
            const int n = cnt[d];
            float v[4], m = -1e30f;
            for (int s = 0; s < n; ++s) {
                float e = esed[hh][srcs[d][s]] + esed[hh][4 + d];
                e = (e >= 0.f) ? e : 0.2f * e;        // leaky_relu 0.2
                v[s] = e; m = fmaxf(m, e);
            }
            float den = 0.f;
            for (int s = 0; s < n; ++s) { v[s] = __expf(v[s] - m); den += v[s]; }
            float inv = 1.f / den;
            for (int s = 0; s < n; ++s) alpha_s[hh][d][s] = v[s] * inv;
            for (int s = n; s < 4; ++s) alpha_s[hh][d][s] = 0.f;
        }
        __syncthreads();

        // ---- aggregate per dst into msum[h][d][c]
        const int srcs2[4][4] = {{1,2,3,0},{2,3,1,0},{1,3,2,0},{1,2,3,0}};
#pragma unroll
        for (int d = 0; d < 4; ++d) {
            float s = 0.f;
#pragma unroll
            for (int sl = 0; sl < 4; ++sl)
                s += alpha_s[h][d][sl] * acc[srcs2[d][sl]];
            msum[h][d][c] = s;
        }
        __syncthreads();

        // ---- head mean + bias + residual + LN + ReLU: thread (h,c) owns node d=h
        float gv = 0.25f * (msum[0][h][c] + msum[1][h][c] + msum[2][h][c] + msum[3][h][c])
                 + Bi[c] + X[h][c];
        {
            float s = gv, q = gv * gv;
#pragma unroll
            for (int off = 32; off; off >>= 1) {
                s += __shfl_down(s, off, 64);
                q += __shfl_down(q, off, 64);
            }
            if (lane == 0) { red2[wv][0] = s; red2[wv][1] = q; }
        }
        __syncthreads();
        if (t < 4) {
            float s = red2[4*t][0] + red2[4*t+1][0] + red2[4*t+2][0] + red2[4*t+3][0];
            float q = red2[4*t][1] + red2[4*t+1][1] + red2[4*t+2][1] + red2[4*t+3][1];
            float mu  = s * (1.f / 256.f);
            float var = q * (1.f / 256.f) - mu * mu;
            mu_s[t] = mu; rstd_s[t] = rsqrtf(var + 1e-5f);
        }
        __syncthreads();
        X[h][c] = fmaxf((gv - mu_s[h]) * rstd_s[h] * Ga[c] + Be[c], 0.f);
        __syncthreads();
    }

    // ---- output gate from token node
    if (t < 256) {
        float x = X[0][c];
        scale[(size_t)b * CCH + c] = 1.f + 1.f / (1.f + __expf(-x));
    }
}

// ---------------- Kernel 3: out = x_ful * (1 + sigmoid), nontemporal store ----------------
__global__ __launch_bounds__(256) void apply_kernel(
    const float* __restrict__ xf, const float* __restrict__ scale,
    float* __restrict__ out, int total4)
{
    int idx = blockIdx.x * 256 + threadIdx.x;
    const int stride = gridDim.x * 256;
    const f4* in4 = (const f4*)xf;
    f4* out4 = (f4*)out;
    for (; idx < total4; idx += stride) {
        f4 v = in4[idx];
        const float s = scale[idx >> 10];          // 1024 float4 per (b,c) row
        f4 o = v * s;
        __builtin_nontemporal_store(o, out4 + idx);
    }
}

extern "C" void kernel_launch(void* const* d_in, const int* in_sizes, int n_in,
                              void* d_out, int out_size, void* d_ws, size_t ws_size,
                              hipStream_t stream) {
    const float* x_ful = (const float*)d_in[0];
    const float* rgb   = (const float*)d_in[1];
    const float* dep   = (const float*)d_in[2];
    const float* tok   = (const float*)d_in[3];
    const float* W0  = (const float*)d_in[4];
    const float* as0 = (const float*)d_in[5];
    const float* ad0 = (const float*)d_in[6];
    const float* b0  = (const float*)d_in[7];
    const float* g0  = (const float*)d_in[8];
    const float* be0 = (const float*)d_in[9];
    const float* W1  = (const float*)d_in[10];
    const float* as1 = (const float*)d_in[11];
    const float* ad1 = (const float*)d_in[12];
    const float* b1  = (const float*)d_in[13];
    const float* g1  = (const float*)d_in[14];
    const float* be1 = (const float*)d_in[15];

    float* ws    = (float*)d_ws;
    float* nodes = ws;                 // [32][4][256] = 32768 floats
    float* scale = ws + 32768;         // [32][256]    =  8192 floats
    float* out   = (float*)d_out;

    // rgb+dep first (nontemporal), x_ful last (temporal -> L3-resident for apply)
    poolA_kernel<<<4096, 256, 0, stream>>>(rgb, dep, nodes);
    poolB_kernel<<<2048, 256, 0, stream>>>(x_ful, nodes);
    gat_kernel<<<32, 1024, 0, stream>>>(nodes, tok, scale,
                                        W0, as0, ad0, b0, g0, be0,
                                        W1, as1, ad1, b1, g1, be1);
    const int total4 = 32 * CCH * 64 * 64 / 4;            // 8,388,608 float4
    apply_kernel<<<2048, 256, 0, stream>>>(x_ful, scale, out, total4);
}